// Round 4
// baseline (587.259 us; speedup 1.0000x reference)
//
#include <hip/hip_runtime.h>
#include <hip/hip_bf16.h>

#define NB 2
#define NN 512
#define ND 64
#define NH 128

typedef __attribute__((ext_vector_type(8))) short short8;
typedef __attribute__((ext_vector_type(4))) float f32x4;

__device__ __forceinline__ short f2s(float x) {
    __hip_bfloat16 h = __float2bfloat16(x);
    return *reinterpret_cast<short*>(&h);
}

__device__ __forceinline__ short8 cvt8(const float* p) {
    f32x4 a = *(const f32x4*)p;
    f32x4 b = *(const f32x4*)(p + 4);
    short8 r;
    r[0] = f2s(a[0]); r[1] = f2s(a[1]); r[2] = f2s(a[2]); r[3] = f2s(a[3]);
    r[4] = f2s(b[0]); r[5] = f2s(b[1]); r[6] = f2s(b[2]); r[7] = f2s(b[3]);
    return r;
}

// ---------------------------------------------------------------------------
// Kernel A: hi[bn][h] = node[bn]@W1[:,h];  hjb[bn][h] = node[bn]@W2[:,h] + b_edge[h]
// ---------------------------------------------------------------------------
__global__ __launch_bounds__(128) void pre_kernel(
    const float* __restrict__ node,
    const float* __restrict__ W_edge,
    const float* __restrict__ b_edge,
    float* __restrict__ hi,
    float* __restrict__ hjb)
{
    int bn = blockIdx.x;
    int h = threadIdx.x;
    __shared__ float nrow[ND];
    if (h < ND) nrow[h] = node[bn * ND + h];
    __syncthreads();
    float a1 = 0.f, a2 = b_edge[h];
    #pragma unroll 4
    for (int d = 0; d < ND; d++) {
        float nd = nrow[d];
        a1 += nd * W_edge[d * NH + h];
        a2 += nd * W_edge[(ND + d) * NH + h];
    }
    hi[bn * NH + h] = a1;
    hjb[bn * NH + h] = a2;
}

// ---------------------------------------------------------------------------
// Kernel B: per (b,i): edge_h[j,h] = relu(he[j,h] + hi[i,h] + hjb[j,h])
//           he = ef@W3 via MFMA with W as the A-operand (D: col=j, row=h)
//           message[i,h] = sum_j adj[i,j]*edge_h[j,h]
// W fragments register-resident; dwordx4 stores.
// ---------------------------------------------------------------------------
__global__ __launch_bounds__(256, 3) void edge_kernel(
    const float* __restrict__ ef,       // B,N,N,64 fp32
    const float* __restrict__ adj,      // B,N,N fp32
    const float* __restrict__ W_edge,   // 192,128 fp32
    const float* __restrict__ hi,       // B,N,128 fp32
    const float* __restrict__ hjb,      // B,N,128 fp32
    float* __restrict__ edge_out,       // B,N,N,128 fp32
    float* __restrict__ message)        // B,N,128 fp32
{
    constexpr int WTS = ND + 8;          // 72 shorts/row: 16B-aligned, balanced banks
    __shared__ short WT[NH * WTS];       // WT[h][k] = bf16(W3[k][h])
    __shared__ float msgbuf[4][NH];

    int blk = blockIdx.x;                // b*N + i
    int b = blk >> 9;
    int tid = threadIdx.x;

    for (int t = tid; t < NH * ND; t += 256) {
        int h = t >> 6;
        int k = t & 63;
        WT[h * WTS + k] = f2s(W_edge[(2 * ND + k) * NH + h]);
    }
    __syncthreads();

    int lane = tid & 63;
    int wave = tid >> 6;
    int n = lane & 15;       // A-row (h) on load; D-col (j) on output
    int quad = lane >> 4;

    // Register-resident W3^T A-fragments: wf[ht*2+kf], A[m=h][k]
    short8 wf[16];
    #pragma unroll
    for (int ht = 0; ht < 8; ht++) {
        #pragma unroll
        for (int kf = 0; kf < 2; kf++)
            wf[ht * 2 + kf] = *(const short8*)(WT + (ht * 16 + n) * WTS + kf * 32 + quad * 8);
    }

    f32x4 hi_l[8];
    #pragma unroll
    for (int ht = 0; ht < 8; ht++)
        hi_l[ht] = *(const f32x4*)(hi + blk * NH + ht * 16 + quad * 4);

    float msg[32];
    #pragma unroll
    for (int i = 0; i < 32; i++) msg[i] = 0.f;

    const float* adjrow = adj + (size_t)blk * NN;
    float* outbase = edge_out + (size_t)blk * NN * NH;

    for (int c = 0; c < 8; c++) {
        int jn = wave * 128 + c * 16 + n;
        const float* efp = ef + ((size_t)blk * NN + jn) * ND;
        short8 af0 = cvt8(efp + quad * 8);         // k 0..31
        short8 af1 = cvt8(efp + 32 + quad * 8);    // k 32..63
        float aj = adjrow[jn];
        const float* hjp = hjb + ((size_t)b * NN + jn) * NH;
        float* outp = outbase + (size_t)jn * NH;

        #pragma unroll
        for (int ht = 0; ht < 8; ht++) {
            f32x4 acc = {0.f, 0.f, 0.f, 0.f};
            acc = __builtin_amdgcn_mfma_f32_16x16x32_bf16(wf[ht * 2 + 0], af0, acc, 0, 0, 0);
            acc = __builtin_amdgcn_mfma_f32_16x16x32_bf16(wf[ht * 2 + 1], af1, acc, 0, 0, 0);
            f32x4 hjv = *(const f32x4*)(hjp + ht * 16 + quad * 4);
            f32x4 hiv = hi_l[ht];
            f32x4 outv;
            #pragma unroll
            for (int r = 0; r < 4; r++) {
                float v = acc[r] + hiv[r] + hjv[r];
                v = fmaxf(v, 0.f);
                outv[r] = v;
                msg[ht * 4 + r] += aj * v;     // h = ht*16 + quad*4 + r
            }
            *(f32x4*)(outp + ht * 16 + quad * 4) = outv;
        }
    }

    // Sum over j: lanes differing in n-bits (1,2,4,8) hold different j's.
    #pragma unroll
    for (int i = 0; i < 32; i++) {
        float v = msg[i];
        v += __shfl_xor(v, 1, 64);
        v += __shfl_xor(v, 2, 64);
        v += __shfl_xor(v, 4, 64);
        v += __shfl_xor(v, 8, 64);
        if (n == 0) msgbuf[wave][(i >> 2) * 16 + quad * 4 + (i & 3)] = v;
    }
    __syncthreads();
    if (tid < NH) {
        message[(size_t)blk * NH + tid] =
            msgbuf[0][tid] + msgbuf[1][tid] + msgbuf[2][tid] + msgbuf[3][tid];
    }
}

// ---------------------------------------------------------------------------
// Kernel C: ending[bn][k] = relu(msg[bn]@Wf1[:,k] + node[bn]@Wf2[:,k] + b_feat[k])
// ---------------------------------------------------------------------------
__global__ __launch_bounds__(128) void out_kernel(
    const float* __restrict__ node,
    const float* __restrict__ message,
    const float* __restrict__ W_feat,   // 192,128 fp32
    const float* __restrict__ b_feat,
    float* __restrict__ ending)
{
    int bn = blockIdx.x;
    int k = threadIdx.x;
    __shared__ float mrow[NH];
    __shared__ float nrow[ND];
    mrow[k] = message[(size_t)bn * NH + k];
    if (k < ND) nrow[k] = node[bn * ND + k];
    __syncthreads();
    float acc = b_feat[k];
    #pragma unroll 4
    for (int h = 0; h < NH; h++)
        acc += mrow[h] * W_feat[h * NH + k];
    #pragma unroll 4
    for (int d = 0; d < ND; d++)
        acc += nrow[d] * W_feat[(NH + d) * NH + k];
    ending[(size_t)bn * NH + k] = fmaxf(acc, 0.f);
}

// ---------------------------------------------------------------------------
extern "C" void kernel_launch(void* const* d_in, const int* in_sizes, int n_in,
                              void* d_out, int out_size, void* d_ws, size_t ws_size,
                              hipStream_t stream)
{
    const float* node   = (const float*)d_in[0];
    const float* adj    = (const float*)d_in[1];
    const float* tgt    = (const float*)d_in[2];
    const float* ef     = (const float*)d_in[3];
    // d_in[4] = node_mask (unused by reference)
    const float* W_edge = (const float*)d_in[5];
    const float* b_edge = (const float*)d_in[6];
    const float* W_feat = (const float*)d_in[7];
    const float* b_feat = (const float*)d_in[8];

    float* out_ending = (float*)d_out;                           // B*N*H
    float* out_edge   = out_ending + (size_t)NB * NN * NH;       // B*N*N*H
    float* out_tgt    = out_edge + (size_t)NB * NN * NN * NH;    // B*N*D

    float* hi      = (float*)d_ws;                        // B*N*H fp32
    float* hjb     = hi + (size_t)NB * NN * NH;           // B*N*H fp32
    float* message = hjb + (size_t)NB * NN * NH;          // B*N*H fp32

    pre_kernel<<<NB * NN, NH, 0, stream>>>(node, W_edge, b_edge, hi, hjb);
    edge_kernel<<<NB * NN, 256, 0, stream>>>(ef, adj, W_edge, hi, hjb, out_edge, message);
    out_kernel<<<NB * NN, NH, 0, stream>>>(node, message, W_feat, b_feat, out_ending);
    hipMemcpyAsync(out_tgt, tgt, (size_t)NB * NN * ND * sizeof(float),
                   hipMemcpyDeviceToDevice, stream);
}